// Round 11
// baseline (1111.684 us; speedup 1.0000x reference)
//
#include <hip/hip_runtime.h>
#include <cstdint>

#define NH 16
#define DH 64
#define FF 4096
#define PP 512
#define BB 2048

typedef __bf16 bf16x8 __attribute__((ext_vector_type(8)));
typedef float f32x4 __attribute__((ext_vector_type(4)));
typedef float f32x16 __attribute__((ext_vector_type(16)));
typedef float fl4 __attribute__((ext_vector_type(4)));
typedef unsigned short us4 __attribute__((ext_vector_type(4)));
typedef unsigned int u32x2 __attribute__((ext_vector_type(2)));

__device__ __forceinline__ unsigned short f2bf(float f) {
  unsigned u = __float_as_uint(f);
  u += 0x7FFFu + ((u >> 16) & 1u);
  return (unsigned short)(u >> 16);
}

// pack two f32 -> two bf16 (round-half-up: +0x8000, take high16s via v_perm)
__device__ __forceinline__ unsigned int pkbf(float lo, float hi) {
  unsigned a = __float_as_uint(lo) + 0x8000u;
  unsigned b = __float_as_uint(hi) + 0x8000u;
  return __builtin_amdgcn_perm(b, a, 0x07060302u);
}

// async global->LDS, 16B/lane. LDS dest = wave-uniform base + lane*16;
// global source is per-lane arbitrary (exploited for the XOR swizzle).
__device__ __forceinline__ void gload_lds16(const void* g, void* l) {
  __builtin_amdgcn_global_load_lds(
      (const __attribute__((address_space(1))) void*)g,
      (__attribute__((address_space(3))) void*)(unsigned int)(unsigned long long)l,
      16, 0, 0);
}

__device__ __forceinline__ unsigned sx32(unsigned v) {
  return (unsigned)__shfl_xor((int)v, 32);
}

// convert features + prototypes fp32 -> bf16 (x is consumed fp32 directly)
__global__ void cvt_fp(const float* __restrict__ f, const float* __restrict__ p,
                       unsigned short* __restrict__ fb,
                       unsigned short* __restrict__ pb) {
  const int nf = FF * 1024 / 4, np = PP * 1024 / 4;
  int i = blockIdx.x * blockDim.x + threadIdx.x;
  const fl4* src;
  us4* dst;
  if (i < nf) {
    src = (const fl4*)f + i;
    dst = (us4*)fb + i;
  } else if (i < nf + np) {
    src = (const fl4*)p + (i - nf);
    dst = (us4*)pb + (i - nf);
  } else {
    return;
  }
  fl4 v = *src;
  us4 o;
  o.x = f2bf(v.x); o.y = f2bf(v.y); o.z = f2bf(v.z); o.w = f2bf(v.w);
  *dst = o;
}

// ---------------------------------------------------------------------------
// Phase 1: per-head [P x F, K=64] GEMM on prototypes.
//   Q1 = th*Pw + al*Pp - al,  Q2 = be*Pw   (layout [h][p][f], bf16)
//   pws[h][p] += be * sum_f Pw
// ---------------------------------------------------------------------------
__global__ __launch_bounds__(256, 2) void gemm_proto(
    const unsigned short* __restrict__ Abf, const unsigned short* __restrict__ Fbf,
    unsigned short* __restrict__ O1, unsigned short* __restrict__ O2,
    float* __restrict__ pws,
    const float* __restrict__ theta, const float* __restrict__ alpha,
    const float* __restrict__ beta) {
  const int h = blockIdx.z;
  const int n0 = blockIdx.x * 128;   // f tile
  const int lm0 = blockIdx.y * 128;  // p tile
  const int t = threadIdx.x;

  __shared__ __align__(16) char As[128 * 128];
  __shared__ __align__(16) char Bs[128 * 128];

  {
    const char* ab = (const char*)(Abf + (size_t)lm0 * 1024 + h * 64);
    const char* bb = (const char*)(Fbf + (size_t)n0 * 1024 + h * 64);
#pragma unroll
    for (int r = 0; r < 4; ++r) {
      int o = r * 4096 + t * 16;
      int row = o >> 7, col = o & 127;
      gload_lds16(ab + (size_t)row * 2048 + col, As + o);
      gload_lds16(bb + (size_t)row * 2048 + col, Bs + o);
    }
  }
  __syncthreads();

  const int wave = t >> 6, lane = t & 63;
  const int wm = wave & 1, wn = wave >> 1;
  const int quad = lane >> 4, lr = lane & 15;

  f32x4 acc[4][4];
#pragma unroll
  for (int i = 0; i < 4; ++i)
#pragma unroll
    for (int j = 0; j < 4; ++j) acc[i][j] = (f32x4){0.f, 0.f, 0.f, 0.f};

#pragma unroll
  for (int s = 0; s < 2; ++s) {
    bf16x8 av[4], bv[4];
#pragma unroll
    for (int fm = 0; fm < 4; ++fm) {
      int row = wm * 64 + fm * 16 + lr;
      av[fm] = *(const bf16x8*)(As + row * 128 + s * 64 + quad * 16);
    }
#pragma unroll
    for (int fn = 0; fn < 4; ++fn) {
      int row = wn * 64 + fn * 16 + lr;
      bv[fn] = *(const bf16x8*)(Bs + row * 128 + s * 64 + quad * 16);
    }
#pragma unroll
    for (int fm = 0; fm < 4; ++fm)
#pragma unroll
      for (int fn = 0; fn < 4; ++fn)
        acc[fm][fn] = __builtin_amdgcn_mfma_f32_16x16x32_bf16(av[fm], bv[fn],
                                                              acc[fm][fn], 0, 0, 0);
  }

  const float th = theta[h], al = alpha[h], be = beta[h];

#pragma unroll
  for (int fm = 0; fm < 4; ++fm) {
    int prow = lm0 + wm * 64 + fm * 16 + quad * 4;
    float rs0 = 0.f, rs1 = 0.f, rs2 = 0.f, rs3 = 0.f;
#pragma unroll
    for (int fn = 0; fn < 4; ++fn) {
      int f = n0 + wn * 64 + fn * 16 + lr;
#pragma unroll
      for (int i = 0; i < 4; ++i) {
        float pf = acc[fm][fn][i];
        float pp = fmaxf(pf, 0.f);
        float pw = pf * pp;
        size_t idx = ((size_t)(h * PP + prow + i)) * FF + f;
        O1[idx] = f2bf(th * pw + al * pp - al);
        O2[idx] = f2bf(be * pw);
        if (i == 0) rs0 += pw;
        else if (i == 1) rs1 += pw;
        else if (i == 2) rs2 += pw;
        else rs3 += pw;
      }
    }
    float rs[4] = {rs0, rs1, rs2, rs3};
#pragma unroll
    for (int i = 0; i < 4; ++i) {
      float s = rs[i];
      s += __shfl_xor(s, 1);
      s += __shfl_xor(s, 2);
      s += __shfl_xor(s, 4);
      s += __shfl_xor(s, 8);
      if (lr == 0) atomicAdd(&pws[h * PP + prow + i], be * s);
    }
  }
}

// ---------------------------------------------------------------------------
// Fused main, round-15 (resubmit; round-10 bench was an infra failure):
// sX LDS round-trip ELIMINATED via in-register relayout.
//   Rounds 2-8: every schedule variant pinned at ~300us / 46% MfmaUtil; the
//   one invariant structural element was the Xw/Xp LDS round-trip + its
//   cross-wave barrier coupling. This version removes it:
//   - Each wave owns a 32-b strip. B-step computed as
//     mfma_32x32x16(A=F[32f x 16d], B=Xh[16d x 32b]) -> C[f][b] with
//     col=b=lane&31: the SAME lane owns b for both B-output and D-A-input.
//   - C->A relayout in-register: C rows f(r) = (r&3) + 8*(r>>2) + 4*half;
//     D A-frag needs f = dks*16 + half*8 + j. Element math (pairs):
//       ks frag words: w0 = half ? sx(B0) : A0 ; w1 = half ? sx(B1) : A1
//                      w2 = half ? B0 : sx(A0) ; w3 = half ? B1 : sx(A1)
//     where A0=pk(c[8k+0],c[8k+1]), A1=pk(c[8k+2],c[8k+3]),
//           B0=pk(c[8k+4],c[8k+5]), B1=pk(c[8k+6],c[8k+7]),
//     sx = __shfl_xor(.,32) (half-wave exchange; known-good primitive).
//   - D: acc[nt] += Xw.Q1^T + Xp.Q2^T, A from registers, B (Q) from global
//     (L2-hit via XCD grouping). All frag layouts identical to the
//     refcheck-passing round-7 kernel (A m=el,k=half*8+j; B n=el; C col=el).
//   - LDS = sF only (2x4KB); per-body barrier protects only the sF DMA.
//     No cross-wave data dependency besides sF.
//   Tile 128b x 128p, wave = 32b x 128p, acc[4 nt] f32x16 = 64 regs.
//   Grid 1024 = 16b x 4p x 16h = exactly 2 full residency rounds (no tail).
// ---------------------------------------------------------------------------
__global__ __launch_bounds__(256, 2) void fused_main(
    const float* __restrict__ x, const unsigned short* __restrict__ f_bf,
    const unsigned short* __restrict__ Q1, const unsigned short* __restrict__ Q2,
    const float* __restrict__ pws, float* __restrict__ out) {
  // XCD-aware decode: all 16 b-blocks of a (p-tile, head) group on one XCD,
  // fully co-resident within a dispatch round.
  const int l = blockIdx.x;             // 0..1023
  const int i = l >> 3;                 // 0..127 within XCD
  const int g = (l & 7) * 8 + (i >> 4); // group = (p-tile, head), 0..63
  const int h = g >> 2;
  const int n0 = (g & 3) * 128;         // p tile
  const int m0 = (i & 15) * 128;        // b tile
  const int t = threadIdx.x;
  const int wave = t >> 6, lane = t & 63;
  const int el = lane & 31, half = lane >> 5;

  __shared__ __align__(16) char sF[2 * 4096];

  // Xh B-operand frags for the B-step: lane el holds x[b = m0+wave*32+el],
  // d = ks*16 + half*8 + j.  4 ks x 4 VGPR = 16 regs.
  bf16x8 xh[4];
  {
    const float* xr = x + (size_t)(m0 + wave * 32 + el) * 1024 + h * 64;
#pragma unroll
    for (int ks = 0; ks < 4; ++ks) {
      const float* p8 = xr + ks * 16 + half * 8;
      fl4 v0 = *(const fl4*)p8;
      fl4 v1 = *(const fl4*)(p8 + 4);
      union { unsigned u[4]; bf16x8 v; } cv;
      cv.u[0] = pkbf(v0.x, v0.y);
      cv.u[1] = pkbf(v0.z, v0.w);
      cv.u[2] = pkbf(v1.x, v1.y);
      cv.u[3] = pkbf(v1.z, v1.w);
      xh[ks] = cv.v;
    }
  }

  // B-step A-frag reads from sF: row = f = el, 16B chunk ks*2+half,
  // physical chunk = logical ^ (el&7) (matches the global-side swizzle).
  int afo[4];
#pragma unroll
  for (int ks = 0; ks < 4; ++ks)
    afo[ks] = el * 128 + (((ks * 2 + half) ^ (el & 7)) * 16);

  // sF staging source (swizzle applied on the GLOBAL side)
  const char* srcF;
  {
    int row = t >> 3, c = t & 7, cs = c ^ (row & 7);
    srcF = (const char*)f_bf + h * 128 + (size_t)row * 2048 + cs * 16;
  }

  // Q: lane (el,half) loads Q[p = n0 + nt*32 + el][f = it*32 + dks*16 + half*8 ..+7]
  const char* qb1 = (const char*)Q1 + (size_t)(h * PP + n0) * FF * 2;
  const char* qb2 = (const char*)Q2 + (size_t)(h * PP + n0) * FF * 2;
  unsigned qo = (unsigned)(((unsigned)el * FF + half * 8) * 2);

  f32x16 acc[4];
#pragma unroll
  for (int nt = 0; nt < 4; ++nt)
#pragma unroll
    for (int r = 0; r < 16; ++r) acc[nt][r] = 0.f;

  union U8 { unsigned u[4]; bf16x8 v; };

  // ---- prologue: tile 0 -> sF buf0 ----
  gload_lds16(srcF, sF + t * 16);
  srcF += 32 * 2048;
  asm volatile("s_waitcnt vmcnt(0)\n\ts_barrier" ::: "memory");
  __builtin_amdgcn_sched_barrier(0);

#define BODY(CUR, NXT) do {                                                  \
    /* stage next tile into the buffer we just finished reading last iter */ \
    gload_lds16(srcF, sF + (NXT) * 4096 + t * 16);                           \
    srcF += 32 * 2048;                                                       \
    /* Q loads for this iteration (consumed by D below; L2-hit) */           \
    bf16x8 q1v[4][2], q2v[4][2];                                             \
    _Pragma("unroll") for (int nt_ = 0; nt_ < 4; ++nt_)                      \
      _Pragma("unroll") for (int dk_ = 0; dk_ < 2; ++dk_) {                  \
        q1v[nt_][dk_] =                                                      \
            *(const bf16x8*)(qb1 + qo + nt_ * 262144 + dk_ * 32);            \
        q2v[nt_][dk_] =                                                      \
            *(const bf16x8*)(qb2 + qo + nt_ * 262144 + dk_ * 32);            \
      }                                                                      \
    qo += 64;                                                                \
    /* B-step: Xf[32f x 32b] = F . Xh over d=64 (4 x 32x32x16 MFMA) */       \
    f32x16 cf;                                                               \
    _Pragma("unroll") for (int r_ = 0; r_ < 16; ++r_) cf[r_] = 0.f;          \
    _Pragma("unroll") for (int ks_ = 0; ks_ < 4; ++ks_) {                    \
      bf16x8 af_ = *(const bf16x8*)(sF + (CUR) * 4096 + afo[ks_]);           \
      cf = __builtin_amdgcn_mfma_f32_32x32x16_bf16(af_, xh[ks_], cf, 0, 0, 0);\
    }                                                                        \
    /* transform + in-register relayout to D A-frags */                      \
    U8 xw[2], xp[2];                                                         \
    _Pragma("unroll") for (int ks_ = 0; ks_ < 2; ++ks_) {                    \
      float p0_ = fmaxf(cf[ks_ * 8 + 0], 0.f), p1_ = fmaxf(cf[ks_ * 8 + 1], 0.f); \
      float p2_ = fmaxf(cf[ks_ * 8 + 2], 0.f), p3_ = fmaxf(cf[ks_ * 8 + 3], 0.f); \
      float p4_ = fmaxf(cf[ks_ * 8 + 4], 0.f), p5_ = fmaxf(cf[ks_ * 8 + 5], 0.f); \
      float p6_ = fmaxf(cf[ks_ * 8 + 6], 0.f), p7_ = fmaxf(cf[ks_ * 8 + 7], 0.f); \
      float w0_ = cf[ks_ * 8 + 0] * p0_, w1_ = cf[ks_ * 8 + 1] * p1_;        \
      float w2_ = cf[ks_ * 8 + 2] * p2_, w3_ = cf[ks_ * 8 + 3] * p3_;        \
      float w4_ = cf[ks_ * 8 + 4] * p4_, w5_ = cf[ks_ * 8 + 5] * p5_;        \
      float w6_ = cf[ks_ * 8 + 6] * p6_, w7_ = cf[ks_ * 8 + 7] * p7_;        \
      unsigned wA0 = pkbf(w0_, w1_), wA1 = pkbf(w2_, w3_);                   \
      unsigned wB0 = pkbf(w4_, w5_), wB1 = pkbf(w6_, w7_);                   \
      unsigned pA0 = pkbf(p0_, p1_), pA1 = pkbf(p2_, p3_);                   \
      unsigned pB0 = pkbf(p4_, p5_), pB1 = pkbf(p6_, p7_);                   \
      unsigned swA0 = sx32(wA0), swA1 = sx32(wA1);                           \
      unsigned swB0 = sx32(wB0), swB1 = sx32(wB1);                           \
      unsigned spA0 = sx32(pA0), spA1 = sx32(pA1);                           \
      unsigned spB0 = sx32(pB0), spB1 = sx32(pB1);                           \
      xw[ks_].u[0] = half ? swB0 : wA0;                                      \
      xw[ks_].u[1] = half ? swB1 : wA1;                                      \
      xw[ks_].u[2] = half ? wB0 : swA0;                                      \
      xw[ks_].u[3] = half ? wB1 : swA1;                                      \
      xp[ks_].u[0] = half ? spB0 : pA0;                                      \
      xp[ks_].u[1] = half ? spB1 : pA1;                                      \
      xp[ks_].u[2] = half ? pB0 : spA0;                                      \
      xp[ks_].u[3] = half ? pB1 : spA1;                                      \
    }                                                                        \
    /* D: acc[nt] += Xw.Q1^T + Xp.Q2^T (16 x 32x32x16 MFMA) */               \
    __builtin_amdgcn_s_setprio(1);                                           \
    _Pragma("unroll") for (int dk_ = 0; dk_ < 2; ++dk_)                      \
      _Pragma("unroll") for (int nt_ = 0; nt_ < 4; ++nt_) {                  \
        acc[nt_] = __builtin_amdgcn_mfma_f32_32x32x16_bf16(                  \
            xw[dk_].v, q1v[nt_][dk_], acc[nt_], 0, 0, 0);                    \
        acc[nt_] = __builtin_amdgcn_mfma_f32_32x32x16_bf16(                  \
            xp[dk_].v, q2v[nt_][dk_], acc[nt_], 0, 0, 0);                    \
      }                                                                      \
    __builtin_amdgcn_s_setprio(0);                                           \
    /* barrier protects only the sF DMA double-buffer (vmcnt drains it; */   \
    /* Q loads already consumed). lgkmcnt closes the 4 sF ds_reads. */       \
    asm volatile("s_waitcnt vmcnt(0) lgkmcnt(0)\n\ts_barrier" ::: "memory"); \
    __builtin_amdgcn_sched_barrier(0);                                       \
  } while (0)

  for (int it2 = 0; it2 < FF / 64; ++it2) {
    BODY(0, 1);
    BODY(1, 0);
  }

  // epilogue: subtract pws, store fp32 (32x32 C/D layout: col=p=el,
  // row b = gi*8 + 4*half + r)
#pragma unroll
  for (int nt = 0; nt < 4; ++nt) {
    int p = n0 + nt * 32 + el;
    float sub = pws[h * PP + p];
#pragma unroll
    for (int gi = 0; gi < 4; ++gi) {
#pragma unroll
      for (int r = 0; r < 4; ++r) {
        int b = m0 + wave * 32 + gi * 8 + half * 4 + r;
        out[(size_t)b * (NH * PP) + h * PP + p] = acc[nt][gi * 4 + r] - sub;
      }
    }
  }
}

extern "C" void kernel_launch(void* const* d_in, const int* in_sizes, int n_in,
                              void* d_out, int out_size, void* d_ws, size_t ws_size,
                              hipStream_t stream) {
  const float* x = (const float*)d_in[0];
  const float* features = (const float*)d_in[1];
  const float* prototypes = (const float*)d_in[2];
  const float* theta = (const float*)d_in[3];
  const float* alpha = (const float*)d_in[4];
  const float* beta = (const float*)d_in[5];
  float* out = (float*)d_out;

  char* ws = (char*)d_ws;
  size_t off = 0;
  auto carve = [&](size_t bytes) -> char* {
    char* p = ws + off;
    off += (bytes + 255) & ~(size_t)255;
    return p;
  };
  // f_bf padded by 64 rows: fused_main's loop prefetches one tile past the
  // end (data unused; keeps the main loop branch-free).
  unsigned short* f_bf = (unsigned short*)carve((size_t)(FF + 64) * 1024 * 2);
  unsigned short* p_bf = (unsigned short*)carve((size_t)PP * 1024 * 2);
  unsigned short* Q1 = (unsigned short*)carve((size_t)NH * PP * FF * 2);
  unsigned short* Q2 = (unsigned short*)carve((size_t)NH * PP * FF * 2);
  float* pws = (float*)carve((size_t)NH * PP * 4);

  const int ncvt = (FF + PP) * 1024 / 4;
  cvt_fp<<<(ncvt + 255) / 256, 256, 0, stream>>>(features, prototypes, f_bf, p_bf);
  hipMemsetAsync(pws, 0, (size_t)NH * PP * 4, stream);

  // Phase 1: prototypes -> Q1, Q2, pws
  gemm_proto<<<dim3(FF / 128, PP / 128, NH), 256, 0, stream>>>(
      p_bf, f_bf, Q1, Q2, pws, theta, alpha, beta);

  // Fused main GEMM (1-D grid, XCD-aware decode in-kernel; 1024 blocks)
  fused_main<<<dim3(1024, 1, 1), 256, 0, stream>>>(
      x, f_bf, Q1, Q2, pws, out);
}